// Round 1
// baseline (8319.531 us; speedup 1.0000x reference)
//
#include <hip/hip_runtime.h>

#define SEQ_LEN 256
#define SPIKE_STEPS 7
#define BATCH 128
#define IN_DIM 96
#define HIDDEN 512
#define OUT_DIM 2

// Transpose W [rows x cols] -> WT [cols x rows]
__global__ void transpose_kernel(const float* __restrict__ in, float* __restrict__ out,
                                 int rows, int cols) {
    int idx = blockIdx.x * blockDim.x + threadIdx.x;
    if (idx < rows * cols) {
        int r = idx / cols, c = idx - r * cols;
        out[c * rows + r] = in[idx];
    }
}

// One workgroup per batch element; thread tid owns hidden unit h = tid in every layer.
__launch_bounds__(512, 1)
__global__ void snn_kernel(const float* __restrict__ x,     // [256,128,96]
                           const float* __restrict__ Wout,  // [2,512]
                           const float* __restrict__ betas, // [3]
                           const float* __restrict__ thrs,  // [3]
                           const float* __restrict__ W0T,   // [96,512]
                           const float* __restrict__ W1T,   // [512,512] (transposed: [j][h])
                           const float* __restrict__ W2T,   // [512,512]
                           float* __restrict__ out)         // [256,128,2]
{
    const int b    = blockIdx.x;
    const int tid  = threadIdx.x;
    const int lane = tid & 63;
    const int wid  = tid >> 6;

    __shared__ float xs[IN_DIM];
    __shared__ unsigned long long zm[8];   // 512-bit spike mask, h-ordered
    __shared__ int act[HIDDEN];            // compact ascending active-index list
    __shared__ float red[16];              // 8 waves x 2 outputs

    const float beta0 = betas[0], beta1 = betas[1], beta2 = betas[2];
    const float thr0  = thrs[0],  thr1  = thrs[1],  thr2  = thrs[2];

    const float wo0 = Wout[tid];            // Wout[0][tid]
    const float wo1 = Wout[HIDDEN + tid];   // Wout[1][tid]

    float mem0 = 0.f, mem1 = 0.f, mem2 = 0.f;
    float mo0 = 0.f, mo1 = 0.f;   // integrator membrane (thread 0 only)

    for (int i = 0; i < SEQ_LEN; ++i) {
        if (tid < IN_DIM) xs[tid] = x[(i * BATCH + b) * IN_DIM + tid];
        __syncthreads();  // B0

        // cur0[h] = sum_k x[k] * W0[h][k]  (constant over the 7 spike steps)
        float cur0 = 0.f;
        #pragma unroll 8
        for (int k = 0; k < IN_DIM; ++k)
            cur0 = __fmaf_rn(xs[k], W0T[k * HIDDEN + tid], cur0);

        float so0 = 0.f, so1 = 0.f;  // per-seq-step sum of mem_out (thread 0 only)

        for (int s = 0; s < SPIKE_STEPS; ++s) {
            // ---- layer 0 LIF ----
            {
                bool reset = (mem0 - thr0) > 0.f;
                mem0 = reset ? 0.f : __fadd_rn(__fmul_rn(beta0, mem0), cur0);
            }
            bool z0 = (mem0 - thr0) > 0.f;
            if (lane == 0) zm[wid] = 0ull;           // will overwrite below
            unsigned long long bal = __ballot(z0);
            if (lane == 0) zm[wid] = bal;
            __syncthreads();  // B1: masks visible

            // build ascending compact list of active j's
            int nact0;
            {
                int pre = 0, total = 0;
                #pragma unroll
                for (int q = 0; q < 8; ++q) {
                    int p = __popcll(zm[q]);
                    total += p;
                    if (q < wid) pre += p;
                }
                unsigned long long myw = zm[wid];
                int rank = pre + __popcll(myw & ((1ull << lane) - 1ull));
                if (z0) act[rank] = tid;
                nact0 = total;
            }
            __syncthreads();  // B2: act list visible

            // ---- layer 1 current: in-order sum of active W1 rows ----
            float cur1 = 0.f;
            {
                int n = 0;
                for (; n + 3 < nact0; n += 4) {
                    int j0 = act[n], j1 = act[n + 1], j2 = act[n + 2], j3 = act[n + 3];
                    float a0 = W1T[j0 * HIDDEN + tid];
                    float a1 = W1T[j1 * HIDDEN + tid];
                    float a2 = W1T[j2 * HIDDEN + tid];
                    float a3 = W1T[j3 * HIDDEN + tid];
                    cur1 = __fadd_rn(cur1, a0);
                    cur1 = __fadd_rn(cur1, a1);
                    cur1 = __fadd_rn(cur1, a2);
                    cur1 = __fadd_rn(cur1, a3);
                }
                for (; n < nact0; ++n)
                    cur1 = __fadd_rn(cur1, W1T[act[n] * HIDDEN + tid]);
            }

            // ---- layer 1 LIF ----
            {
                bool reset = (mem1 - thr1) > 0.f;
                mem1 = reset ? 0.f : __fadd_rn(__fmul_rn(beta1, mem1), cur1);
            }
            bool z1 = (mem1 - thr1) > 0.f;
            {
                unsigned long long bal1 = __ballot(z1);
                if (lane == 0) zm[wid] = bal1;
            }
            __syncthreads();  // B3

            int nact1;
            {
                int pre = 0, total = 0;
                #pragma unroll
                for (int q = 0; q < 8; ++q) {
                    int p = __popcll(zm[q]);
                    total += p;
                    if (q < wid) pre += p;
                }
                unsigned long long myw = zm[wid];
                int rank = pre + __popcll(myw & ((1ull << lane) - 1ull));
                if (z1) act[rank] = tid;
                nact1 = total;
            }
            __syncthreads();  // B4

            // ---- layer 2 current ----
            float cur2 = 0.f;
            {
                int n = 0;
                for (; n + 3 < nact1; n += 4) {
                    int j0 = act[n], j1 = act[n + 1], j2 = act[n + 2], j3 = act[n + 3];
                    float a0 = W2T[j0 * HIDDEN + tid];
                    float a1 = W2T[j1 * HIDDEN + tid];
                    float a2 = W2T[j2 * HIDDEN + tid];
                    float a3 = W2T[j3 * HIDDEN + tid];
                    cur2 = __fadd_rn(cur2, a0);
                    cur2 = __fadd_rn(cur2, a1);
                    cur2 = __fadd_rn(cur2, a2);
                    cur2 = __fadd_rn(cur2, a3);
                }
                for (; n < nact1; ++n)
                    cur2 = __fadd_rn(cur2, W2T[act[n] * HIDDEN + tid]);
            }

            // ---- layer 2 LIF ----
            {
                bool reset = (mem2 - thr2) > 0.f;
                mem2 = reset ? 0.f : __fadd_rn(__fmul_rn(beta2, mem2), cur2);
            }
            bool z2 = (mem2 - thr2) > 0.f;

            // ---- output integrator: mem_out += z2 @ Wout.T ----
            float c0 = z2 ? wo0 : 0.f;
            float c1 = z2 ? wo1 : 0.f;
            #pragma unroll
            for (int off = 32; off > 0; off >>= 1) {
                c0 += __shfl_down(c0, off);
                c1 += __shfl_down(c1, off);
            }
            if (lane == 0) { red[wid * 2] = c0; red[wid * 2 + 1] = c1; }
            __syncthreads();  // B5
            if (tid == 0) {
                float r0 = 0.f, r1 = 0.f;
                #pragma unroll
                for (int q = 0; q < 8; ++q) { r0 += red[q * 2]; r1 += red[q * 2 + 1]; }
                mo0 += r0; mo1 += r1;
                so0 += mo0; so1 += mo1;
            }
        }

        if (tid == 0) {
            out[(i * BATCH + b) * OUT_DIM + 0] = so0 / 7.0f;
            out[(i * BATCH + b) * OUT_DIM + 1] = so1 / 7.0f;
        }
    }
}

extern "C" void kernel_launch(void* const* d_in, const int* in_sizes, int n_in,
                              void* d_out, int out_size, void* d_ws, size_t ws_size,
                              hipStream_t stream) {
    const float* x     = (const float*)d_in[0];
    const float* W0    = (const float*)d_in[1];
    const float* W1    = (const float*)d_in[2];
    const float* W2    = (const float*)d_in[3];
    const float* Wout  = (const float*)d_in[4];
    const float* betas = (const float*)d_in[5];
    const float* thrs  = (const float*)d_in[6];
    float* out = (float*)d_out;

    float* ws  = (float*)d_ws;
    float* W0T = ws;                               // 96*512
    float* W1T = W0T + IN_DIM * HIDDEN;            // 512*512
    float* W2T = W1T + HIDDEN * HIDDEN;            // 512*512

    {
        int n = HIDDEN * IN_DIM;
        transpose_kernel<<<(n + 255) / 256, 256, 0, stream>>>(W0, W0T, HIDDEN, IN_DIM);
    }
    {
        int n = HIDDEN * HIDDEN;
        transpose_kernel<<<(n + 255) / 256, 256, 0, stream>>>(W1, W1T, HIDDEN, HIDDEN);
        transpose_kernel<<<(n + 255) / 256, 256, 0, stream>>>(W2, W2T, HIDDEN, HIDDEN);
    }

    snn_kernel<<<BATCH, HIDDEN, 0, stream>>>(x, Wout, betas, thrs, W0T, W1T, W2T, out);
}

// Round 2
// 4808.409 us; speedup vs baseline: 1.7302x; 1.7302x over previous
//
#include <hip/hip_runtime.h>

#define SEQ_LEN 256
#define SPIKE_STEPS 7
#define T_TOTAL (SEQ_LEN * SPIKE_STEPS)
#define BATCH 128
#define IN_DIM 96
#define HIDDEN 512
#define OUT_DIM 2

// d_ws layout (floats for weights, then sync area):
//   W0T [96*512] | W1T [512*512] | W2T [512*512] | ctr[128] (zeroed) | zbuf[B][T][8] u64
#define W0T_OFF 0
#define W1T_OFF (IN_DIM * HIDDEN)
#define W2T_OFF (W1T_OFF + HIDDEN * HIDDEN)
#define CTR_BYTE_OFF ((size_t)(W2T_OFF + HIDDEN * HIDDEN) * sizeof(float))  // 2,293,760
#define ZBUF_BYTE_OFF (CTR_BYTE_OFF + 1024)

// Transpose W [rows x cols] -> WT [cols x rows]
__global__ void transpose_kernel(const float* __restrict__ in, float* __restrict__ out,
                                 int rows, int cols) {
    int idx = blockIdx.x * blockDim.x + threadIdx.x;
    if (idx < rows * cols) {
        int r = idx / cols, c = idx - r * cols;
        out[c * rows + r] = in[idx];
    }
}

// 256 blocks: even = producer (layer0+layer1 for batch b), odd = consumer (layer2+output).
// Coupling: z1 masks, write-once slots zbuf[b][t][0..7], published with relaxed
// agent-scope (sc1) atomic stores; progress counter ctr[b] stored after the
// __syncthreads() vmcnt-drain, so mask data is at the coherent point before the
// counter advances. Consumer reads masks with relaxed agent-scope loads (bypass
// stale L1/L2) — no acquire-invalidate, so the W2 working set stays L2-resident.
__launch_bounds__(512, 1)
__global__ void snn_pipe_kernel(const float* __restrict__ x,     // [256,128,96]
                                const float* __restrict__ Wout,  // [2,512]
                                const float* __restrict__ betas, // [3]
                                const float* __restrict__ thrs,  // [3]
                                const float* __restrict__ W0T,   // [96,512]
                                const float* __restrict__ W1T,   // [512,512]
                                const float* __restrict__ W2T,   // [512,512]
                                unsigned long long* __restrict__ zbuf,
                                int* __restrict__ ctr,
                                float* __restrict__ out)         // [256,128,2]
{
    const int b    = blockIdx.x >> 1;
    const int role = blockIdx.x & 1;
    const int tid  = threadIdx.x;
    const int lane = tid & 63;
    const int wid  = tid >> 6;

    __shared__ float xs[IN_DIM];
    __shared__ unsigned long long zm[8];
    __shared__ int act[HIDDEN];
    __shared__ float red[16];

    if (role == 0) {
        // ---------------- producer: layer0 (autonomous) + layer1 ----------------
        const float beta0 = betas[0], beta1 = betas[1];
        const float thr0  = thrs[0],  thr1  = thrs[1];
        float mem0 = 0.f, mem1 = 0.f;
        unsigned long long* zb = zbuf + (size_t)b * T_TOTAL * 8;

        for (int i = 0; i < SEQ_LEN; ++i) {
            if (tid < IN_DIM) xs[tid] = x[(i * BATCH + b) * IN_DIM + tid];
            __syncthreads();

            float cur0 = 0.f;
            #pragma unroll 8
            for (int k = 0; k < IN_DIM; ++k)
                cur0 = __fmaf_rn(xs[k], W0T[k * HIDDEN + tid], cur0);

            for (int s = 0; s < SPIKE_STEPS; ++s) {
                const int t = i * SPIKE_STEPS + s;

                // layer 0 LIF
                bool reset0 = (mem0 - thr0) > 0.f;
                mem0 = reset0 ? 0.f : __fadd_rn(__fmul_rn(beta0, mem0), cur0);
                bool z0 = (mem0 - thr0) > 0.f;
                unsigned long long bal = __ballot(z0);
                if (lane == 0) zm[wid] = bal;
                __syncthreads();

                // ascending compact active list
                int nact;
                {
                    int pre = 0, total = 0;
                    #pragma unroll
                    for (int q = 0; q < 8; ++q) {
                        int p = __popcll(zm[q]);
                        total += p;
                        if (q < wid) pre += p;
                    }
                    int rank = pre + __popcll(zm[wid] & ((1ull << lane) - 1ull));
                    if (z0) act[rank] = tid;
                    nact = total;
                }
                __syncthreads();

                // layer1 current: in-order sum of active W1 rows
                float cur1 = 0.f;
                int n = 0;
                for (; n + 7 < nact; n += 8) {
                    float a0 = W1T[act[n    ] * HIDDEN + tid];
                    float a1 = W1T[act[n + 1] * HIDDEN + tid];
                    float a2 = W1T[act[n + 2] * HIDDEN + tid];
                    float a3 = W1T[act[n + 3] * HIDDEN + tid];
                    float a4 = W1T[act[n + 4] * HIDDEN + tid];
                    float a5 = W1T[act[n + 5] * HIDDEN + tid];
                    float a6 = W1T[act[n + 6] * HIDDEN + tid];
                    float a7 = W1T[act[n + 7] * HIDDEN + tid];
                    cur1 = __fadd_rn(cur1, a0);
                    cur1 = __fadd_rn(cur1, a1);
                    cur1 = __fadd_rn(cur1, a2);
                    cur1 = __fadd_rn(cur1, a3);
                    cur1 = __fadd_rn(cur1, a4);
                    cur1 = __fadd_rn(cur1, a5);
                    cur1 = __fadd_rn(cur1, a6);
                    cur1 = __fadd_rn(cur1, a7);
                }
                for (; n < nact; ++n)
                    cur1 = __fadd_rn(cur1, W1T[act[n] * HIDDEN + tid]);

                // layer 1 LIF
                bool reset1 = (mem1 - thr1) > 0.f;
                mem1 = reset1 ? 0.f : __fadd_rn(__fmul_rn(beta1, mem1), cur1);
                bool z1 = (mem1 - thr1) > 0.f;

                // publish z1 mask (sc1 stores -> coherent point)
                unsigned long long bal1 = __ballot(z1);
                if (lane == 0)
                    __hip_atomic_store(&zb[(size_t)t * 8 + wid], bal1,
                                       __ATOMIC_RELAXED, __HIP_MEMORY_SCOPE_AGENT);
                __syncthreads();   // vmcnt(0) drain before barrier => masks visible
                if (tid == 0)
                    __hip_atomic_store(&ctr[b], t + 1,
                                       __ATOMIC_RELAXED, __HIP_MEMORY_SCOPE_AGENT);
            }
        }
    } else {
        // ---------------- consumer: layer2 + output integrator ----------------
        const float beta2 = betas[2];
        const float thr2  = thrs[2];
        const float wo0 = Wout[tid];
        const float wo1 = Wout[HIDDEN + tid];
        float mem2 = 0.f, mo0 = 0.f, mo1 = 0.f;
        const unsigned long long* zb = zbuf + (size_t)b * T_TOTAL * 8;

        for (int i = 0; i < SEQ_LEN; ++i) {
            float so0 = 0.f, so1 = 0.f;

            for (int s = 0; s < SPIKE_STEPS; ++s) {
                const int t = i * SPIKE_STEPS + s;

                if (tid == 0) {
                    while (__hip_atomic_load(&ctr[b], __ATOMIC_RELAXED,
                                             __HIP_MEMORY_SCOPE_AGENT) < t + 1)
                        __builtin_amdgcn_s_sleep(1);
                }
                __syncthreads();

                if (tid < 8)
                    zm[tid] = __hip_atomic_load(&zb[(size_t)t * 8 + tid],
                                                __ATOMIC_RELAXED, __HIP_MEMORY_SCOPE_AGENT);
                __syncthreads();

                bool z1 = (zm[wid] >> lane) & 1ull;
                int nact;
                {
                    int pre = 0, total = 0;
                    #pragma unroll
                    for (int q = 0; q < 8; ++q) {
                        int p = __popcll(zm[q]);
                        total += p;
                        if (q < wid) pre += p;
                    }
                    int rank = pre + __popcll(zm[wid] & ((1ull << lane) - 1ull));
                    if (z1) act[rank] = tid;
                    nact = total;
                }
                __syncthreads();

                // layer2 current: in-order sum of active W2 rows
                float cur2 = 0.f;
                int n = 0;
                for (; n + 7 < nact; n += 8) {
                    float a0 = W2T[act[n    ] * HIDDEN + tid];
                    float a1 = W2T[act[n + 1] * HIDDEN + tid];
                    float a2 = W2T[act[n + 2] * HIDDEN + tid];
                    float a3 = W2T[act[n + 3] * HIDDEN + tid];
                    float a4 = W2T[act[n + 4] * HIDDEN + tid];
                    float a5 = W2T[act[n + 5] * HIDDEN + tid];
                    float a6 = W2T[act[n + 6] * HIDDEN + tid];
                    float a7 = W2T[act[n + 7] * HIDDEN + tid];
                    cur2 = __fadd_rn(cur2, a0);
                    cur2 = __fadd_rn(cur2, a1);
                    cur2 = __fadd_rn(cur2, a2);
                    cur2 = __fadd_rn(cur2, a3);
                    cur2 = __fadd_rn(cur2, a4);
                    cur2 = __fadd_rn(cur2, a5);
                    cur2 = __fadd_rn(cur2, a6);
                    cur2 = __fadd_rn(cur2, a7);
                }
                for (; n < nact; ++n)
                    cur2 = __fadd_rn(cur2, W2T[act[n] * HIDDEN + tid]);

                // layer 2 LIF
                bool reset2 = (mem2 - thr2) > 0.f;
                mem2 = reset2 ? 0.f : __fadd_rn(__fmul_rn(beta2, mem2), cur2);
                bool z2 = (mem2 - thr2) > 0.f;

                // output integrator: mem_out += z2 @ Wout.T
                float c0 = z2 ? wo0 : 0.f;
                float c1 = z2 ? wo1 : 0.f;
                #pragma unroll
                for (int off = 32; off > 0; off >>= 1) {
                    c0 += __shfl_down(c0, off);
                    c1 += __shfl_down(c1, off);
                }
                if (lane == 0) { red[wid * 2] = c0; red[wid * 2 + 1] = c1; }
                __syncthreads();
                if (tid == 0) {
                    float r0 = 0.f, r1 = 0.f;
                    #pragma unroll
                    for (int q = 0; q < 8; ++q) { r0 += red[q * 2]; r1 += red[q * 2 + 1]; }
                    mo0 += r0; mo1 += r1;
                    so0 += mo0; so1 += mo1;
                }
            }

            if (tid == 0) {
                out[(i * BATCH + b) * OUT_DIM + 0] = so0 / 7.0f;
                out[(i * BATCH + b) * OUT_DIM + 1] = so1 / 7.0f;
            }
        }
    }
}

extern "C" void kernel_launch(void* const* d_in, const int* in_sizes, int n_in,
                              void* d_out, int out_size, void* d_ws, size_t ws_size,
                              hipStream_t stream) {
    const float* x     = (const float*)d_in[0];
    const float* W0    = (const float*)d_in[1];
    const float* W1    = (const float*)d_in[2];
    const float* W2    = (const float*)d_in[3];
    const float* Wout  = (const float*)d_in[4];
    const float* betas = (const float*)d_in[5];
    const float* thrs  = (const float*)d_in[6];
    float* out = (float*)d_out;

    float* ws  = (float*)d_ws;
    float* W0T = ws + W0T_OFF;
    float* W1T = ws + W1T_OFF;
    float* W2T = ws + W2T_OFF;
    int* ctr = (int*)((char*)d_ws + CTR_BYTE_OFF);
    unsigned long long* zbuf = (unsigned long long*)((char*)d_ws + ZBUF_BYTE_OFF);

    {
        int n = HIDDEN * IN_DIM;
        transpose_kernel<<<(n + 255) / 256, 256, 0, stream>>>(W0, W0T, HIDDEN, IN_DIM);
    }
    {
        int n = HIDDEN * HIDDEN;
        transpose_kernel<<<(n + 255) / 256, 256, 0, stream>>>(W1, W1T, HIDDEN, HIDDEN);
        transpose_kernel<<<(n + 255) / 256, 256, 0, stream>>>(W2, W2T, HIDDEN, HIDDEN);
    }

    // progress counters must start at 0 every launch (ws is re-poisoned 0xAA)
    hipMemsetAsync((char*)d_ws + CTR_BYTE_OFF, 0, 1024, stream);

    snn_pipe_kernel<<<2 * BATCH, HIDDEN, 0, stream>>>(
        x, Wout, betas, thrs, W0T, W1T, W2T, zbuf, ctr, out);
}